// Round 7
// baseline (323.617 us; speedup 1.0000x reference)
//
#include <hip/hip_runtime.h>

typedef __attribute__((ext_vector_type(8))) short s16x8;
typedef __attribute__((ext_vector_type(4))) float f32x4;

#define CCH 128

__device__ __forceinline__ ushort f2bf(float f) {
  uint u = __float_as_uint(f);
  u += 0x7fffu + ((u >> 16) & 1u);
  return (ushort)(u >> 16);
}
__device__ __forceinline__ float bf2f(ushort u) {
  return __uint_as_float(((uint)u) << 16);
}

// ---------- pass1: stats + NCHW fp32 -> NHWC bf16 transpose copy (proven r3-r5) ----------
__global__ __launch_bounds__(256) void pass1_stats_tr(const float* __restrict__ x,
                                                      ushort* __restrict__ xb,
                                                      float2* __restrict__ partials) {
  __shared__ ushort sT[256 * CCH];  // 64 KiB, [px][ch], 8B-granule XOR swizzle
  __shared__ float ws1[4][8], ws2[4][8];
  const int t = threadIdx.x;
  const int b = blockIdx.x >> 8;
  const int p0 = (blockIdx.x & 255) << 8;
  const int wv = t >> 6, lane = t & 63;
  const int px4 = lane << 2;
  float sg1[8], sg2[8];
#pragma unroll
  for (int g = 0; g < 8; ++g) { sg1[g] = 0.f; sg2[g] = 0.f; }

  const float* xbase = x + (((size_t)b * CCH) << 16) + p0;
#pragma unroll
  for (int i = 0; i < 8; ++i) {
    const int ch = i * 16 + wv * 4;
    float4 v[4];
#pragma unroll
    for (int j = 0; j < 4; ++j)
      v[j] = *(const float4*)(xbase + (((size_t)(ch + j)) << 16) + px4);
#pragma unroll
    for (int j = 0; j < 4; ++j) {
      sg1[i] += v[j].x + v[j].y + v[j].z + v[j].w;
      sg2[i] += v[j].x * v[j].x + v[j].y * v[j].y + v[j].z * v[j].z + v[j].w * v[j].w;
    }
#pragma unroll
    for (int k = 0; k < 4; ++k) {
      const int row = px4 + k;
      const int gs = (i * 4 + wv) ^ (((row >> 3) & 15) << 1);
      ushort4 pk;
      pk.x = f2bf(((const float*)&v[0])[k]);
      pk.y = f2bf(((const float*)&v[1])[k]);
      pk.z = f2bf(((const float*)&v[2])[k]);
      pk.w = f2bf(((const float*)&v[3])[k]);
      *(ushort4*)&sT[row * CCH + gs * 4] = pk;
    }
  }
#pragma unroll
  for (int g = 0; g < 8; ++g) {
    float a = sg1[g], q = sg2[g];
#pragma unroll
    for (int off = 32; off > 0; off >>= 1) {
      a += __shfl_down(a, off);
      q += __shfl_down(q, off);
    }
    if (lane == 0) { ws1[wv][g] = a; ws2[wv][g] = q; }
  }
  __syncthreads();
  if (t < 8) {
    float a = ws1[0][t] + ws1[1][t] + ws1[2][t] + ws1[3][t];
    float q = ws2[0][t] + ws2[1][t] + ws2[2][t] + ws2[3][t];
    partials[blockIdx.x * 8 + t] = (float2){a, q};
  }
  const int c16 = t & 15, pr = t >> 4;
  ushort* dst = xb + ((size_t)((b << 16) + p0)) * CCH;
#pragma unroll
  for (int s = 0; s < 16; ++s) {
    const int row = s * 16 + pr;
    const int gs = (c16 * 2) ^ (((row >> 3) & 15) << 1);
    *(s16x8*)&dst[(size_t)row * CCH + c16 * 8] = *(const s16x8*)&sT[row * CCH + gs * 4];
  }
}

// ---------- finalize + weight prep (proven) ----------
__global__ void stats_finalize2(const float2* __restrict__ partials,
                                const float* __restrict__ gn_w,
                                const float* __restrict__ gn_b,
                                float* __restrict__ scale, float* __restrict__ shift) {
  const int t = threadIdx.x;
  const int b = t >> 3, g = t & 7;
  float s1 = 0.f, s2 = 0.f;
  for (int c = 0; c < 256; ++c) {
    float2 p = partials[(b * 256 + c) * 8 + g];
    s1 += p.x;
    s2 += p.y;
  }
  const float invN = 1.0f / 1048576.0f;
  const float mean = s1 * invN;
  const float var = s2 * invN - mean * mean;
  const float rstd = rsqrtf(var + 1e-5f);
  for (int i = 0; i < 16; ++i) {
    const int c = g * 16 + i;
    const float sc = rstd * gn_w[c];
    scale[b * CCH + c] = sc;
    shift[b * CCH + c] = gn_b[c] - mean * sc;
  }
}

__global__ __launch_bounds__(256) void prep_w2(const float* __restrict__ w2,
                                               ushort* __restrict__ w2b) {
  int i = blockIdx.x * 256 + threadIdx.x;
  float4 a = ((const float4*)w2)[i];
  ushort4 o;
  o.x = f2bf(a.x); o.y = f2bf(a.y); o.z = f2bf(a.z); o.w = f2bf(a.w);
  ((ushort4*)w2b)[i] = o;
}

__global__ __launch_bounds__(128) void fold_w1(const float* __restrict__ w1,
                                               const float* __restrict__ b1,
                                               const float* __restrict__ scale,
                                               const float* __restrict__ shift,
                                               ushort* __restrict__ W1b,
                                               float* __restrict__ c1) {
  const int b = blockIdx.x >> 7, o = blockIdx.x & 127, c = threadIdx.x;
  const float wv = w1[o * CCH + c];
  W1b[(b << 14) + o * CCH + c] = f2bf(wv * scale[b * CCH + c]);
  float s = wv * shift[b * CCH + c];
#pragma unroll
  for (int off = 32; off > 0; off >>= 1) s += __shfl_down(s, off);
  __shared__ float tmp[2];
  if ((threadIdx.x & 63) == 0) tmp[threadIdx.x >> 6] = s;
  __syncthreads();
  if (threadIdx.x == 0) c1[(b << 7) + o] = tmp[0] + tmp[1] + b1[o];
}

// ---------- pass2: per-wave pixel ownership; barriers only in epilogue (lgkm-only) ----------
// 4096 blocks (XCD<->batch swizzle), 256 thr = 4 waves, 32 KiB LDS, 4 blocks/CU.
// Wave wv owns px [wv*32, wv*32+32): stage -> GEMM1(all 128 H-ch) -> wave-private
// H transpose -> GEMM2(all 128 out-ch) run with NO barriers. Epilogue: cooperative
// fp32 [64ch][128px] transpose (2 rounds) with 4 lgkm-only barriers -> 512B stores.
__global__ __launch_bounds__(256, 4) void wavepipe(
    const ushort* __restrict__ xb, const ushort* __restrict__ W1b,
    const ushort* __restrict__ w2b, const float* __restrict__ c1,
    const float* __restrict__ b2, float* __restrict__ out) {
  __shared__ ushort sl[4][4096];  // 4 x 8 KiB wave slices; epilogue overlays fp32 [64][128]
  float* sF = (float*)&sl[0][0];
  const int t = threadIdx.x, lane = t & 63, wv = t >> 6;
  const int fl = lane & 15, fh = lane >> 4;
  const int blk = ((blockIdx.x & 7) << 9) | (blockIdx.x >> 3);  // XCD k <-> batch k
  const int b = blk >> 9;
  const int p0 = (blk & 511) << 7;
  const int pw = p0 + wv * 32;
  ushort* slice = &sl[wv][0];

  // ---- stage: 8 x 1 KiB contiguous NHWC reads -> swizzled wave slice [32px][128ch] ----
  const ushort* src = xb + ((size_t)((b << 16) + pw)) * CCH;
#pragma unroll
  for (int i = 0; i < 8; ++i) {
    const int px = i * 4 + (lane >> 4);
    const int g = lane & 15;
    const s16x8 v = *(const s16x8*)(src + px * CCH + g * 8);
    *(s16x8*)&slice[px * CCH + ((g ^ (px & 7)) * 8)] = v;
  }

  // ---- GEMM1: acc[to][tp] = W1' . x for ALL 128 out-ch, own 32 px ----
  f32x4 acc[8][2];
#pragma unroll
  for (int to = 0; to < 8; ++to)
#pragma unroll
    for (int tp = 0; tp < 2; ++tp) acc[to][tp] = (f32x4){0.f, 0.f, 0.f, 0.f};

  const ushort* w1p = W1b + (b << 14);
#pragma unroll
  for (int k0 = 0; k0 < 4; ++k0) {
    const int kb = k0 * 32 + fh * 8;
    const int gb = k0 * 4 + fh;  // granule index of this k-octet
    const s16x8 bt0 = *(const s16x8*)&slice[fl * CCH + ((gb ^ (fl & 7)) * 8)];
    const s16x8 bt1 = *(const s16x8*)&slice[(16 + fl) * CCH + ((gb ^ (fl & 7)) * 8)];
#pragma unroll
    for (int to = 0; to < 8; ++to) {
      const s16x8 a = *(const s16x8*)(w1p + (to * 16 + fl) * CCH + kb);
      acc[to][0] = __builtin_amdgcn_mfma_f32_16x16x32_bf16(a, bt0, acc[to][0], 0, 0, 0);
      acc[to][1] = __builtin_amdgcn_mfma_f32_16x16x32_bf16(a, bt1, acc[to][1], 0, 0, 0);
    }
  }

  // ---- wave-private: capture residual, overwrite slice with H = relu(acc + c1) ----
  ushort4 rx[8][2];
  const float* c1b = c1 + (b << 7);
#pragma unroll
  for (int to = 0; to < 8; ++to) {
    const int ob = to * 16 + fh * 4;
    const float4 cc = *(const float4*)(c1b + ob);
    const int gq = to * 2 + (fh >> 1);  // granule of ch-quad
    const int hq = (fh & 1) * 4;        // half-granule elem offset
#pragma unroll
    for (int tp = 0; tp < 2; ++tp) {
      const int px = tp * 16 + fl;
      ushort* p = &slice[px * CCH + (gq ^ (px & 7)) * 8 + hq];
      rx[to][tp] = *(const ushort4*)p;
      ushort4 pk;
      pk.x = f2bf(fmaxf(acc[to][tp][0] + cc.x, 0.f));
      pk.y = f2bf(fmaxf(acc[to][tp][1] + cc.y, 0.f));
      pk.z = f2bf(fmaxf(acc[to][tp][2] + cc.z, 0.f));
      pk.w = f2bf(fmaxf(acc[to][tp][3] + cc.w, 0.f));
      *(ushort4*)p = pk;
    }
  }

  // ---- GEMM2: acc2 = w2 . H (H wave-local in slice) ----
  f32x4 acc2[8][2];
#pragma unroll
  for (int to = 0; to < 8; ++to)
#pragma unroll
    for (int tp = 0; tp < 2; ++tp) acc2[to][tp] = (f32x4){0.f, 0.f, 0.f, 0.f};

#pragma unroll
  for (int k0 = 0; k0 < 4; ++k0) {
    const int kb = k0 * 32 + fh * 8;
    const int gb = k0 * 4 + fh;
    const s16x8 bt0 = *(const s16x8*)&slice[fl * CCH + ((gb ^ (fl & 7)) * 8)];
    const s16x8 bt1 = *(const s16x8*)&slice[(16 + fl) * CCH + ((gb ^ (fl & 7)) * 8)];
#pragma unroll
    for (int to = 0; to < 8; ++to) {
      const s16x8 a = *(const s16x8*)(w2b + (to * 16 + fl) * CCH + kb);
      acc2[to][0] = __builtin_amdgcn_mfma_f32_16x16x32_bf16(a, bt0, acc2[to][0], 0, 0, 0);
      acc2[to][1] = __builtin_amdgcn_mfma_f32_16x16x32_bf16(a, bt1, acc2[to][1], 0, 0, 0);
    }
  }

  // ---- epilogue: 2 rounds of cooperative fp32 transpose -> 512B-contiguous stores ----
  const int pxb = wv * 32;
#pragma unroll
  for (int f = 0; f < 2; ++f) {
    // all waves done with slice reads (f=0: GEMM2; f=1: round-0 buffer reads)
    asm volatile("s_waitcnt lgkmcnt(0)" ::: "memory");
    __builtin_amdgcn_s_barrier();
#pragma unroll
    for (int to4 = 0; to4 < 4; ++to4) {
      const int to = f * 4 + to4;
      const int chb = to * 16 + fh * 4;
      const float4 bb = *(const float4*)(b2 + chb);
#pragma unroll
      for (int tp = 0; tp < 2; ++tp) {
        const int px = pxb + tp * 16 + fl;
        const int g = px >> 2, e = px & 3;
        float v0 = acc2[to][tp][0] + bb.x + bf2f(rx[to][tp].x);
        float v1 = acc2[to][tp][1] + bb.y + bf2f(rx[to][tp].y);
        float v2 = acc2[to][tp][2] + bb.z + bf2f(rx[to][tp].z);
        float v3 = acc2[to][tp][3] + bb.w + bf2f(rx[to][tp].w);
        const int r0 = to4 * 16 + fh * 4;
        sF[(r0 + 0) * 128 + ((g ^ ((r0 + 0) & 7)) << 2) + e] = v0;
        sF[(r0 + 1) * 128 + ((g ^ ((r0 + 1) & 7)) << 2) + e] = v1;
        sF[(r0 + 2) * 128 + ((g ^ ((r0 + 2) & 7)) << 2) + e] = v2;
        sF[(r0 + 3) * 128 + ((g ^ ((r0 + 3) & 7)) << 2) + e] = v3;
      }
    }
    asm volatile("s_waitcnt lgkmcnt(0)" ::: "memory");
    __builtin_amdgcn_s_barrier();  // buffer ready
#pragma unroll
    for (int i = 0; i < 8; ++i) {
      const int rd = wv * 16 + i * 2 + (lane >> 5);
      const int g = lane & 31;
      const f32x4 v = *(const f32x4*)&sF[rd * 128 + ((g ^ (rd & 7)) << 2)];
      *(f32x4*)(out + (((size_t)(b * CCH + f * 64 + rd)) << 16) + p0 + g * 4) = v;
    }
  }
}

// ---------- launcher ----------
extern "C" void kernel_launch(void* const* d_in, const int* in_sizes, int n_in,
                              void* d_out, int out_size, void* d_ws, size_t ws_size,
                              hipStream_t stream) {
  const float* x    = (const float*)d_in[0];
  const float* gn_w = (const float*)d_in[1];
  const float* gn_b = (const float*)d_in[2];
  const float* w1   = (const float*)d_in[3];
  const float* b1   = (const float*)d_in[4];
  const float* w2   = (const float*)d_in[5];
  const float* b2   = (const float*)d_in[6];
  float* out = (float*)d_out;
  char* ws = (char*)d_ws;

  const size_t XB = (size_t)8 * 65536 * CCH * 2;  // 128 MiB NHWC bf16
  ushort* xbuf  = (ushort*)ws;
  float2* parts = (float2*)(ws + XB);
  float* scale  = (float*)(ws + XB + 131072);
  float* shift  = (float*)(ws + XB + 135168);
  ushort* w2b   = (ushort*)(ws + XB + 139264);
  ushort* W1b   = (ushort*)(ws + XB + 172032);
  float* c1     = (float*)(ws + XB + 434176);

  hipLaunchKernelGGL(pass1_stats_tr, dim3(2048), dim3(256), 0, stream, x, xbuf, parts);
  hipLaunchKernelGGL(stats_finalize2, dim3(1), dim3(64), 0, stream, parts, gn_w, gn_b, scale, shift);
  hipLaunchKernelGGL(fold_w1, dim3(1024), dim3(128), 0, stream, w1, b1, scale, shift, W1b, c1);
  hipLaunchKernelGGL(prep_w2, dim3(16), dim3(256), 0, stream, w2, w2b);
  hipLaunchKernelGGL(wavepipe, dim3(4096), dim3(256), 0, stream, xbuf, W1b, w2b, c1, b2, out);
}

// Round 8
// 264.382 us; speedup vs baseline: 1.2241x; 1.2241x over previous
//
#include <hip/hip_runtime.h>

typedef __attribute__((ext_vector_type(8))) short s16x8;
typedef __attribute__((ext_vector_type(4))) float f32x4;
typedef unsigned int u32;

#define CCH 128

__device__ __forceinline__ ushort f2bf(float f) {
  uint u = __float_as_uint(f);
  u += 0x7fffu + ((u >> 16) & 1u);
  return (ushort)(u >> 16);
}
__device__ __forceinline__ float bf2f(ushort u) {
  return __uint_as_float(((uint)u) << 16);
}

// swizzled element index into a [row][128] bf16 tile (8-elem granule XOR)
__device__ __forceinline__ int swz(int row, int col) {
  return (row << 7) | (col ^ ((row & 7) << 3));
}

__device__ __forceinline__ void gll16(const void* g, void* l) {
  __builtin_amdgcn_global_load_lds((const __attribute__((address_space(1))) u32*)g,
                                   (__attribute__((address_space(3))) u32*)l, 16, 0, 0);
}

// ---------------- pass1: stats + NCHW fp32 -> pre-swizzled bf16 tile images (r6-proven) ----------------
__global__ __launch_bounds__(256) void pass1(const float* __restrict__ x,
                                             ushort* __restrict__ xb,
                                             float2* __restrict__ partials) {
  __shared__ ushort sT[128 * CCH];  // 32 KiB, internal granule4 swizzle
  __shared__ float wsa[4][4], wsb[4][4];
  const int t = threadIdx.x;
  const int blk = ((blockIdx.x & 7) << 9) | (blockIdx.x >> 3);  // bijective
  const int b = blk >> 9;
  const int p0 = (blk & 511) << 7;
  const int wv = t >> 6, lane = t & 63;
  const int px4 = (t & 31) * 4;
  const int c8 = t >> 5;  // 0..7

  float sa[4], sq[4];
#pragma unroll
  for (int i = 0; i < 4; ++i) { sa[i] = 0.f; sq[i] = 0.f; }

  const float* xbase = x + (((size_t)b * CCH) << 16) + p0;
#pragma unroll
  for (int i = 0; i < 4; ++i) {
    const int ch = i * 32 + c8 * 4;
    float4 v[4];
#pragma unroll
    for (int j = 0; j < 4; ++j)
      v[j] = *(const float4*)(xbase + (((size_t)(ch + j)) << 16) + px4);
#pragma unroll
    for (int j = 0; j < 4; ++j) {
      sa[i] += v[j].x + v[j].y + v[j].z + v[j].w;
      sq[i] += v[j].x * v[j].x + v[j].y * v[j].y + v[j].z * v[j].z + v[j].w * v[j].w;
    }
    const int c4 = i * 8 + c8;
#pragma unroll
    for (int k = 0; k < 4; ++k) {
      const int row = px4 + k;
      const int gs = c4 ^ (((row >> 3) & 15) << 1);
      ushort4 pk;
      pk.x = f2bf(((const float*)&v[0])[k]);
      pk.y = f2bf(((const float*)&v[1])[k]);
      pk.z = f2bf(((const float*)&v[2])[k]);
      pk.w = f2bf(((const float*)&v[3])[k]);
      *(ushort4*)&sT[row * CCH + gs * 4] = pk;
    }
  }
#pragma unroll
  for (int i = 0; i < 4; ++i) {
    float a = sa[i], q = sq[i];
#pragma unroll
    for (int off = 32; off > 0; off >>= 1) {
      a += __shfl_down(a, off);
      q += __shfl_down(q, off);
    }
    if (lane == 0) { wsa[wv][i] = a; wsb[wv][i] = q; }
  }
  __syncthreads();
  if (t < 8) {
    const int g = t;
    const int w0 = (g & 1) * 2, ii = g >> 1;
    partials[blk * 8 + g] =
        (float2){wsa[w0][ii] + wsa[w0 + 1][ii], wsb[w0][ii] + wsb[w0 + 1][ii]};
  }
  const int g = t & 15, pr = t >> 4;
  ushort* dst = xb + ((size_t)blk << 14);
#pragma unroll
  for (int s = 0; s < 8; ++s) {
    const int row = s * 16 + pr;
    const int sidx = row * CCH + (((2 * g) ^ (((row >> 3) & 15) << 1)) * 4);
    const int didx = row * CCH + ((g ^ (row & 7)) * 8);
    *(s16x8*)&dst[didx] = *(const s16x8*)&sT[sidx];
  }
}

// ---------------- finalize + weight prep (proven) ----------------
__global__ void stats_finalize2(const float2* __restrict__ partials,
                                const float* __restrict__ gn_w,
                                const float* __restrict__ gn_b,
                                float* __restrict__ scale, float* __restrict__ shift) {
  const int t = threadIdx.x;
  const int b = t >> 3, g = t & 7;
  float s1 = 0.f, s2 = 0.f;
  for (int c = 0; c < 512; ++c) {
    float2 p = partials[(b * 512 + c) * 8 + g];
    s1 += p.x;
    s2 += p.y;
  }
  const float invN = 1.0f / 1048576.0f;
  const float mean = s1 * invN;
  const float var = s2 * invN - mean * mean;
  const float rstd = rsqrtf(var + 1e-5f);
  for (int i = 0; i < 16; ++i) {
    const int c = g * 16 + i;
    const float sc = rstd * gn_w[c];
    scale[b * CCH + c] = sc;
    shift[b * CCH + c] = gn_b[c] - mean * sc;
  }
}

__global__ __launch_bounds__(256) void prep_w2(const float* __restrict__ w2,
                                               ushort* __restrict__ w2b) {
  int i = blockIdx.x * 256 + threadIdx.x;
  float4 a = ((const float4*)w2)[i];
  ushort4 o;
  o.x = f2bf(a.x); o.y = f2bf(a.y); o.z = f2bf(a.z); o.w = f2bf(a.w);
  ((ushort4*)w2b)[i] = o;
}

__global__ __launch_bounds__(128) void fold_w1(const float* __restrict__ w1,
                                               const float* __restrict__ b1,
                                               const float* __restrict__ scale,
                                               const float* __restrict__ shift,
                                               ushort* __restrict__ W1b,
                                               float* __restrict__ c1) {
  const int b = blockIdx.x >> 7, o = blockIdx.x & 127, c = threadIdx.x;
  const float wv = w1[o * CCH + c];
  W1b[(b << 14) + o * CCH + c] = f2bf(wv * scale[b * CCH + c]);
  float s = wv * shift[b * CCH + c];
#pragma unroll
  for (int off = 32; off > 0; off >>= 1) s += __shfl_down(s, off);
  __shared__ float tmp[2];
  if ((threadIdx.x & 63) == 0) tmp[threadIdx.x >> 6] = s;
  __syncthreads();
  if (threadIdx.x == 0) c1[(b << 7) + o] = tmp[0] + tmp[1] + b1[o];
}

// ---------------- pass2: persistent 2-deep pipeline, exact counted vmcnt ----------------
// 512 blocks (2/CU, XCD k <-> batch k), 8 tiles each, 2 x 32 KiB LDS double buffer.
// Per-wave vmem per tile (order pinned by sched_barrier): 8 prefetch gll + 16
// weight b128 loads + 32 float2 stores. Tile-top wait: vmcnt(56) steady /
// vmcnt(48) last — stores NEVER drained inside the loop.
#define NT 8
__global__ __launch_bounds__(256) void mlp_pipe(
    const ushort* __restrict__ xb, const ushort* __restrict__ W1b,
    const ushort* __restrict__ w2b, const float* __restrict__ c1,
    const float* __restrict__ b2, float* __restrict__ out) {
  __shared__ ushort sB[2][128 * CCH];  // 64 KiB
  const int t = threadIdx.x, lane = t & 63, wv = t >> 6;
  const int fl = lane & 15, fh = lane >> 4;
  const int blk = ((blockIdx.x & 7) << 6) | (blockIdx.x >> 3);  // bijective
  const int gt0 = blk * NT;
  const int b = gt0 >> 9;
  const ushort* w1p = W1b + (b << 14);

  // hoisted per-block constants (retired before the loop)
  float4 cc[2], bb[2];
#pragma unroll
  for (int f = 0; f < 2; ++f) {
    const int ob = wv * 32 + f * 16 + fh * 4;
    cc[f] = *(const float4*)(c1 + (b << 7) + ob);
    bb[f] = *(const float4*)(b2 + ob);
  }

  // prologue: stage tile 0 into buf 0, drain once
  {
    const char* s0 = (const char*)xb + ((size_t)gt0 << 15) + wv * 8192 + lane * 16;
    ushort* l0 = &sB[0][wv * 4096];
#pragma unroll
    for (int i = 0; i < 8; ++i) gll16(s0 + i * 1024, l0 + i * 512);
  }
  __builtin_amdgcn_sched_barrier(0);
  asm volatile("s_waitcnt vmcnt(0)" ::: "memory");
  __builtin_amdgcn_sched_barrier(0);
  __builtin_amdgcn_s_barrier();
  __builtin_amdgcn_sched_barrier(0);

#pragma unroll 1
  for (int it = 0; it < NT; ++it) {
    const int cur = it & 1;
    const int gt = gt0 + it;
    if (it + 1 < NT) {  // issue next-tile prefetch (stays in flight across this tile)
      const char* s0 = (const char*)xb + ((size_t)(gt + 1) << 15) + wv * 8192 + lane * 16;
      ushort* l0 = &sB[cur ^ 1][wv * 4096];
#pragma unroll
      for (int i = 0; i < 8; ++i) gll16(s0 + i * 1024, l0 + i * 512);
    }
    __builtin_amdgcn_sched_barrier(0);
    if (it > 0) {
      if (it + 1 < NT) {
        asm volatile("s_waitcnt vmcnt(56)" ::: "memory");  // 16 wt + 32 st + 8 pf after pf(it)
      } else {
        asm volatile("s_waitcnt vmcnt(48)" ::: "memory");  // 16 wt + 32 st after pf(it)
      }
    }
    __builtin_amdgcn_sched_barrier(0);
    __builtin_amdgcn_s_barrier();  // B1: buf[cur] ready (it==0 drained in prologue)
    __builtin_amdgcn_sched_barrier(0);

    ushort* sb = &sB[cur][0];

    // ---- GEMM1: H = W1' . x ----
    f32x4 acc[2][8];
#pragma unroll
    for (int f = 0; f < 2; ++f)
#pragma unroll
      for (int j = 0; j < 8; ++j) acc[f][j] = (f32x4){0.f, 0.f, 0.f, 0.f};
#pragma unroll
    for (int k0 = 0; k0 < 128; k0 += 32) {
      const int kb = k0 + fh * 8;
      const s16x8 a0 = *(const s16x8*)(w1p + (wv * 32 + fl) * CCH + kb);
      const s16x8 a1 = *(const s16x8*)(w1p + (wv * 32 + 16 + fl) * CCH + kb);
#pragma unroll
      for (int j = 0; j < 8; ++j) {
        const s16x8 bf = *(const s16x8*)&sb[swz(j * 16 + fl, kb)];
        acc[0][j] = __builtin_amdgcn_mfma_f32_16x16x32_bf16(a0, bf, acc[0][j], 0, 0, 0);
        acc[1][j] = __builtin_amdgcn_mfma_f32_16x16x32_bf16(a1, bf, acc[1][j], 0, 0, 0);
      }
    }
    asm volatile("s_waitcnt lgkmcnt(0)" ::: "memory");
    __builtin_amdgcn_sched_barrier(0);
    __builtin_amdgcn_s_barrier();  // B2: all waves done reading xn
    __builtin_amdgcn_sched_barrier(0);

    // ---- wb: capture residual to regs, overwrite with H = relu(acc + c1) ----
    ushort4 rx[2][8];
#pragma unroll
    for (int f = 0; f < 2; ++f) {
      const int ob = wv * 32 + f * 16 + fh * 4;
#pragma unroll
      for (int j = 0; j < 8; ++j) {
        ushort* p = &sb[swz(j * 16 + fl, ob)];
        rx[f][j] = *(const ushort4*)p;  // residual (read before overwrite, same thread)
        ushort4 pk;
        pk.x = f2bf(fmaxf(acc[f][j][0] + cc[f].x, 0.f));
        pk.y = f2bf(fmaxf(acc[f][j][1] + cc[f].y, 0.f));
        pk.z = f2bf(fmaxf(acc[f][j][2] + cc[f].z, 0.f));
        pk.w = f2bf(fmaxf(acc[f][j][3] + cc[f].w, 0.f));
        *(ushort4*)p = pk;
      }
    }
    asm volatile("s_waitcnt lgkmcnt(0)" ::: "memory");
    __builtin_amdgcn_sched_barrier(0);
    __builtin_amdgcn_s_barrier();  // B3: H ready
    __builtin_amdgcn_sched_barrier(0);

    // ---- GEMM2: ffn = w2 . H ----
    f32x4 acc2[2][8];
#pragma unroll
    for (int f = 0; f < 2; ++f)
#pragma unroll
      for (int j = 0; j < 8; ++j) acc2[f][j] = (f32x4){0.f, 0.f, 0.f, 0.f};
#pragma unroll
    for (int k0 = 0; k0 < 128; k0 += 32) {
      const int kb = k0 + fh * 8;
      const s16x8 a0 = *(const s16x8*)(w2b + (wv * 32 + fl) * CCH + kb);
      const s16x8 a1 = *(const s16x8*)(w2b + (wv * 32 + 16 + fl) * CCH + kb);
#pragma unroll
      for (int j = 0; j < 8; ++j) {
        const s16x8 bf = *(const s16x8*)&sb[swz(j * 16 + fl, kb)];
        acc2[0][j] = __builtin_amdgcn_mfma_f32_16x16x32_bf16(a0, bf, acc2[0][j], 0, 0, 0);
        acc2[1][j] = __builtin_amdgcn_mfma_f32_16x16x32_bf16(a1, bf, acc2[1][j], 0, 0, 0);
      }
    }
    asm volatile("s_waitcnt lgkmcnt(0)" ::: "memory");
    __builtin_amdgcn_sched_barrier(0);
    __builtin_amdgcn_s_barrier();  // B4: H reads done -> sb reusable as fp32 tile
    __builtin_amdgcn_sched_barrier(0);

    // ---- epilogue: out = x + ffn + b2 via wave-private LDS transpose ----
    float* sF = (float*)sb;
    const int p0 = (gt & 511) << 7;
    const int rowbase = wv * 16;
#pragma unroll
    for (int f = 0; f < 2; ++f) {
#pragma unroll
      for (int j = 0; j < 8; ++j) {
        const int rb = (rowbase + fh * 4) * 128 + j * 16 + fl;
        sF[rb]       = acc2[f][j][0] + bb[f].x + bf2f(rx[f][j].x);
        sF[rb + 128] = acc2[f][j][1] + bb[f].y + bf2f(rx[f][j].y);
        sF[rb + 256] = acc2[f][j][2] + bb[f].z + bf2f(rx[f][j].z);
        sF[rb + 384] = acc2[f][j][3] + bb[f].w + bf2f(rx[f][j].w);
      }
#pragma unroll
      for (int i = 0; i < 16; ++i) {
        const float2 v = *(const float2*)&sF[(rowbase + i) * 128 + lane * 2];
        const int ch = wv * 32 + f * 16 + i;
        *(float2*)(out + (((size_t)(b * CCH + ch)) << 16) + p0 + lane * 2) = v;
      }
    }
    asm volatile("s_waitcnt lgkmcnt(0)" ::: "memory");
    __builtin_amdgcn_sched_barrier(0);
    __builtin_amdgcn_s_barrier();  // B5: epilogue LDS done -> next prefetch may write buf
    __builtin_amdgcn_sched_barrier(0);
  }
}

// ---------------- launcher ----------------
extern "C" void kernel_launch(void* const* d_in, const int* in_sizes, int n_in,
                              void* d_out, int out_size, void* d_ws, size_t ws_size,
                              hipStream_t stream) {
  const float* x    = (const float*)d_in[0];
  const float* gn_w = (const float*)d_in[1];
  const float* gn_b = (const float*)d_in[2];
  const float* w1   = (const float*)d_in[3];
  const float* b1   = (const float*)d_in[4];
  const float* w2   = (const float*)d_in[5];
  const float* b2   = (const float*)d_in[6];
  float* out = (float*)d_out;
  char* ws = (char*)d_ws;

  const size_t XB = (size_t)8 * 65536 * CCH * 2;  // 128 MiB pre-swizzled tiles
  ushort* xbuf  = (ushort*)ws;
  float2* parts = (float2*)(ws + XB);             // 256 KiB
  float* scale  = (float*)(ws + XB + 262144);
  float* shift  = (float*)(ws + XB + 266240);
  ushort* w2b   = (ushort*)(ws + XB + 270336);
  ushort* W1b   = (ushort*)(ws + XB + 303104);    // 256 KiB
  float* c1     = (float*)(ws + XB + 565248);

  hipLaunchKernelGGL(pass1, dim3(4096), dim3(256), 0, stream, x, xbuf, parts);
  hipLaunchKernelGGL(stats_finalize2, dim3(1), dim3(64), 0, stream, parts, gn_w, gn_b, scale, shift);
  hipLaunchKernelGGL(fold_w1, dim3(1024), dim3(128), 0, stream, w1, b1, scale, shift, W1b, c1);
  hipLaunchKernelGGL(prep_w2, dim3(16), dim3(256), 0, stream, w2, w2b);
  hipLaunchKernelGGL(mlp_pipe, dim3(512), dim3(256), 0, stream, xbuf, W1b, w2b, c1, b2, out);
}